// Round 1
// baseline (168.658 us; speedup 1.0000x reference)
//
#include <hip/hip_runtime.h>
#include <hip/hip_bf16.h>

#define NUM_GRAPHS 1024
#define NUM_ATOMS  64

// Kernel 1: segment sums + counts.
// Wave layout: lane = 16*q + r, q in [0,4) = node sub-index, r in [0,16) = column group.
// Each lane float4-loads atoms [4r, 4r+4) of node (base + q). Batch is sorted, so
// per-graph partials live in registers and flush (atomicAdd) only at boundaries.
__global__ void __launch_bounds__(256)
seg_sum_kernel(const float4* __restrict__ codes4,   // [nodes][16] float4
               const int* __restrict__ batch,       // [nodes]
               float* __restrict__ sums,            // [NUM_GRAPHS*NUM_ATOMS]
               float* __restrict__ counts,          // [NUM_GRAPHS]
               int total_nodes, int chunk) {
    int tid  = blockIdx.x * blockDim.x + threadIdx.x;
    int wid  = tid >> 6;
    int lane = tid & 63;
    int q = lane >> 4;
    int r = lane & 15;

    long long s = (long long)wid * chunk;
    long long e = s + chunk;
    if (e > total_nodes) e = total_nodes;
    if (s >= e) return;

    float4 acc = make_float4(0.f, 0.f, 0.f, 0.f);
    int g_cur = -1;
    int cnt = 0;

    for (long long base = s; base < e; base += 4) {
        long long n = base + q;
        if (n < e) {
            int g = batch[n];
            if (g != g_cur) {
                if (g_cur >= 0) {
                    float* dst = sums + g_cur * NUM_ATOMS + r * 4;
                    atomicAdd(dst + 0, acc.x);
                    atomicAdd(dst + 1, acc.y);
                    atomicAdd(dst + 2, acc.z);
                    atomicAdd(dst + 3, acc.w);
                    if (r == 0) atomicAdd(counts + g_cur, (float)cnt);
                }
                acc = make_float4(0.f, 0.f, 0.f, 0.f);
                cnt = 0;
                g_cur = g;
            }
            float4 v = codes4[n * 16 + r];
            acc.x += v.x; acc.y += v.y; acc.z += v.z; acc.w += v.w;
            cnt++;
        }
    }
    if (g_cur >= 0) {
        float* dst = sums + g_cur * NUM_ATOMS + r * 4;
        atomicAdd(dst + 0, acc.x);
        atomicAdd(dst + 1, acc.y);
        atomicAdd(dst + 2, acc.z);
        atomicAdd(dst + 3, acc.w);
        if (r == 0) atomicAdd(counts + g_cur, (float)cnt);
    }
}

// Kernel 2: graph_codes = sums/counts; per-atom unbiased variance over 1024
// graphs; mean over atoms; * -0.01. One block, 1024 threads (16 groups x 64 atoms).
__global__ void __launch_bounds__(1024)
finalize_kernel(const float* __restrict__ sums,
                const float* __restrict__ counts,
                float* __restrict__ out) {
    __shared__ float S1[16][NUM_ATOMS];
    __shared__ float S2[16][NUM_ATOMS];
    __shared__ float V[NUM_ATOMS];

    int t = threadIdx.x;
    int a = t & 63;
    int grp = t >> 6;

    float s1 = 0.f, s2 = 0.f;
    for (int g = grp; g < NUM_GRAPHS; g += 16) {
        float x = sums[g * NUM_ATOMS + a] / counts[g];
        s1 += x;
        s2 += x * x;
    }
    S1[grp][a] = s1;
    S2[grp][a] = s2;
    __syncthreads();

    if (t < NUM_ATOMS) {
        float t1 = 0.f, t2 = 0.f;
        for (int k = 0; k < 16; k++) { t1 += S1[k][t]; t2 += S2[k][t]; }
        // unbiased: (sum(x^2) - sum(x)^2/N) / (N-1)
        float var = (t2 - t1 * t1 * (1.0f / NUM_GRAPHS)) * (1.0f / (NUM_GRAPHS - 1));
        V[t] = var;
    }
    __syncthreads();

    if (t == 0) {
        float tot = 0.f;
        for (int k = 0; k < NUM_ATOMS; k++) tot += V[k];
        out[0] = -0.01f * (tot * (1.0f / NUM_ATOMS));
    }
}

extern "C" void kernel_launch(void* const* d_in, const int* in_sizes, int n_in,
                              void* d_out, int out_size, void* d_ws, size_t ws_size,
                              hipStream_t stream) {
    const float* codes = (const float*)d_in[0];
    const int*   batch = (const int*)d_in[1];
    int total_nodes = in_sizes[0] / NUM_ATOMS;

    float* sums   = (float*)d_ws;
    float* counts = sums + NUM_GRAPHS * NUM_ATOMS;

    hipMemsetAsync(d_ws, 0, (NUM_GRAPHS * NUM_ATOMS + NUM_GRAPHS) * sizeof(float), stream);

    const int threads = 256;
    const int blocks  = 2048;                 // 8192 waves: memory-bound, lots of TLP
    int nwaves = blocks * threads / 64;
    int chunk  = (total_nodes + nwaves - 1) / nwaves;

    seg_sum_kernel<<<blocks, threads, 0, stream>>>(
        (const float4*)codes, batch, sums, counts, total_nodes, chunk);

    finalize_kernel<<<1, 1024, 0, stream>>>(sums, counts, (float*)d_out);
}

// Round 2
// 121.460 us; speedup vs baseline: 1.3886x; 1.3886x over previous
//
#include <hip/hip_runtime.h>
#include <hip/hip_bf16.h>

#define NUM_GRAPHS 1024
#define NUM_ATOMS  64

// Kernel 1: one block per graph. Binary-search the sorted batch vector for the
// segment [s0,s1), stream-reduce codes[s0:s1, :] and write the per-graph MEAN
// directly (no atomics, no workspace zeroing, no per-node batch reads).
// Block = 512 threads: t = 16*q + r with q in [0,32) node sub-index,
// r in [0,16) float4 column group. Per iteration the block reads 32 nodes x
// 256 B = 8 KB contiguous.
__global__ void __launch_bounds__(512)
graph_mean_kernel(const float4* __restrict__ codes4,  // [nodes][16] float4
                  const int* __restrict__ batch,      // [nodes], sorted
                  float4* __restrict__ means,         // [NUM_GRAPHS][16] float4
                  int total_nodes) {
    int g = blockIdx.x;

    // lower_bound(batch, g) — all threads redundantly (broadcast loads)
    int lo = 0, hi = total_nodes;
    while (lo < hi) { int mid = (lo + hi) >> 1; if (batch[mid] < g) lo = mid + 1; else hi = mid; }
    int s0 = lo;
    hi = total_nodes;
    while (lo < hi) { int mid = (lo + hi) >> 1; if (batch[mid] < g + 1) lo = mid + 1; else hi = mid; }
    int s1 = lo;

    int t = threadIdx.x;
    int r = t & 15;
    int q = t >> 4;

    float4 acc = make_float4(0.f, 0.f, 0.f, 0.f);
    for (int n = s0 + q; n < s1; n += 32) {
        float4 v = codes4[n * 16 + r];
        acc.x += v.x; acc.y += v.y; acc.z += v.z; acc.w += v.w;
    }

    // Reduce 32 node-subgroups per column. Pad row to 17 float4 to spread banks.
    __shared__ float4 red[32][17];
    red[q][r] = acc;
    __syncthreads();

    if (t < 16) {
        float4 tot = make_float4(0.f, 0.f, 0.f, 0.f);
        #pragma unroll
        for (int k = 0; k < 32; k++) {
            float4 v = red[k][t];
            tot.x += v.x; tot.y += v.y; tot.z += v.z; tot.w += v.w;
        }
        float inv = 1.0f / (float)(s1 - s0);
        means[g * 16 + t] = make_float4(tot.x * inv, tot.y * inv, tot.z * inv, tot.w * inv);
    }
}

// Kernel 2: per-atom unbiased variance over the 1024 graph means, mean over
// atoms, * -0.01. One block, 1024 threads (16 graph-groups x 64 atoms).
__global__ void __launch_bounds__(1024)
finalize_kernel(const float* __restrict__ means,  // [NUM_GRAPHS][NUM_ATOMS]
                float* __restrict__ out) {
    __shared__ float S1[16][NUM_ATOMS];
    __shared__ float S2[16][NUM_ATOMS];
    __shared__ float V[NUM_ATOMS];

    int t = threadIdx.x;
    int a = t & 63;
    int grp = t >> 6;

    float s1 = 0.f, s2 = 0.f;
    for (int g = grp; g < NUM_GRAPHS; g += 16) {
        float x = means[g * NUM_ATOMS + a];
        s1 += x;
        s2 += x * x;
    }
    S1[grp][a] = s1;
    S2[grp][a] = s2;
    __syncthreads();

    if (t < NUM_ATOMS) {
        float t1 = 0.f, t2 = 0.f;
        #pragma unroll
        for (int k = 0; k < 16; k++) { t1 += S1[k][t]; t2 += S2[k][t]; }
        // unbiased: (sum(x^2) - sum(x)^2/N) / (N-1)
        float var = (t2 - t1 * t1 * (1.0f / NUM_GRAPHS)) * (1.0f / (NUM_GRAPHS - 1));
        V[t] = var;
    }
    __syncthreads();

    if (t == 0) {
        float tot = 0.f;
        #pragma unroll
        for (int k = 0; k < NUM_ATOMS; k++) tot += V[k];
        out[0] = -0.01f * (tot * (1.0f / NUM_ATOMS));
    }
}

extern "C" void kernel_launch(void* const* d_in, const int* in_sizes, int n_in,
                              void* d_out, int out_size, void* d_ws, size_t ws_size,
                              hipStream_t stream) {
    const float* codes = (const float*)d_in[0];
    const int*   batch = (const int*)d_in[1];
    int total_nodes = in_sizes[0] / NUM_ATOMS;

    float4* means = (float4*)d_ws;  // NUM_GRAPHS * 16 float4 = 256 KB

    graph_mean_kernel<<<NUM_GRAPHS, 512, 0, stream>>>(
        (const float4*)codes, batch, means, total_nodes);

    finalize_kernel<<<1, 1024, 0, stream>>>((const float*)means, (float*)d_out);
}

// Round 3
// 120.633 us; speedup vs baseline: 1.3981x; 1.0069x over previous
//
#include <hip/hip_runtime.h>
#include <hip/hip_bf16.h>

#define NUM_GRAPHS 1024
#define NUM_ATOMS  64

// Kernel 0: precompute segment boundaries. offs[g] = lower_bound(batch, g).
// offs[1024] = total_nodes. 1025 independent binary searches, fully parallel.
__global__ void __launch_bounds__(256)
bounds_kernel(const int* __restrict__ batch, int* __restrict__ offs, int total_nodes) {
    int g = blockIdx.x * blockDim.x + threadIdx.x;
    if (g > NUM_GRAPHS) return;
    int lo = 0, hi = total_nodes;
    while (lo < hi) { int mid = (lo + hi) >> 1; if (batch[mid] < g) lo = mid + 1; else hi = mid; }
    offs[g] = lo;
}

// Kernel 1: one block per graph. Stream-reduce codes[s0:s1, :], write the mean.
// Block = 512 threads: t = 16*q + r, q in [0,32) node sub-index, r in [0,16)
// float4 column group. 4x unrolled: 4 independent loads in flight per lane.
__global__ void __launch_bounds__(512)
graph_mean_kernel(const float4* __restrict__ codes4,  // [nodes][16] float4
                  const int* __restrict__ offs,       // [NUM_GRAPHS+1]
                  float4* __restrict__ means,         // [NUM_GRAPHS][16] float4
                  int total_nodes) {
    int g = blockIdx.x;
    int s0 = offs[g];
    int s1 = offs[g + 1];

    int t = threadIdx.x;
    int r = t & 15;
    int q = t >> 4;

    const float4* p = codes4 + (long long)(s0 + q) * 16 + r;
    int n = s0 + q;

    float4 a0 = make_float4(0.f, 0.f, 0.f, 0.f);
    float4 a1 = make_float4(0.f, 0.f, 0.f, 0.f);
    float4 a2 = make_float4(0.f, 0.f, 0.f, 0.f);
    float4 a3 = make_float4(0.f, 0.f, 0.f, 0.f);

    // Bulk: 4 nodes per thread per iteration (block covers 128 nodes/step).
    while (n + 96 < s1) {
        float4 v0 = p[0];
        float4 v1 = p[512];
        float4 v2 = p[1024];
        float4 v3 = p[1536];
        a0.x += v0.x; a0.y += v0.y; a0.z += v0.z; a0.w += v0.w;
        a1.x += v1.x; a1.y += v1.y; a1.z += v1.z; a1.w += v1.w;
        a2.x += v2.x; a2.y += v2.y; a2.z += v2.z; a2.w += v2.w;
        a3.x += v3.x; a3.y += v3.y; a3.z += v3.z; a3.w += v3.w;
        n += 128; p += 2048;
    }
    // Tail
    while (n < s1) {
        float4 v = p[0];
        a0.x += v.x; a0.y += v.y; a0.z += v.z; a0.w += v.w;
        n += 32; p += 512;
    }

    float4 acc;
    acc.x = (a0.x + a1.x) + (a2.x + a3.x);
    acc.y = (a0.y + a1.y) + (a2.y + a3.y);
    acc.z = (a0.z + a1.z) + (a2.z + a3.z);
    acc.w = (a0.w + a1.w) + (a2.w + a3.w);

    // Reduce 32 node-subgroups per column. Row padded to 17 float4.
    __shared__ float4 red[32][17];
    red[q][r] = acc;
    __syncthreads();

    if (t < 16) {
        float4 tot = make_float4(0.f, 0.f, 0.f, 0.f);
        #pragma unroll
        for (int k = 0; k < 32; k++) {
            float4 v = red[k][t];
            tot.x += v.x; tot.y += v.y; tot.z += v.z; tot.w += v.w;
        }
        float inv = 1.0f / (float)(s1 - s0);
        means[g * 16 + t] = make_float4(tot.x * inv, tot.y * inv, tot.z * inv, tot.w * inv);
    }
}

// Kernel 2: per-atom unbiased variance over 1024 graph means, mean over atoms,
// * -0.01. One block, 1024 threads (16 graph-groups x 64 atoms).
__global__ void __launch_bounds__(1024)
finalize_kernel(const float* __restrict__ means,  // [NUM_GRAPHS][NUM_ATOMS]
                float* __restrict__ out) {
    __shared__ float S1[16][NUM_ATOMS];
    __shared__ float S2[16][NUM_ATOMS];
    __shared__ float V[NUM_ATOMS];

    int t = threadIdx.x;
    int a = t & 63;
    int grp = t >> 6;

    float s1 = 0.f, s2 = 0.f;
    for (int g = grp; g < NUM_GRAPHS; g += 16) {
        float x = means[g * NUM_ATOMS + a];
        s1 += x;
        s2 += x * x;
    }
    S1[grp][a] = s1;
    S2[grp][a] = s2;
    __syncthreads();

    if (t < NUM_ATOMS) {
        float t1 = 0.f, t2 = 0.f;
        #pragma unroll
        for (int k = 0; k < 16; k++) { t1 += S1[k][t]; t2 += S2[k][t]; }
        float var = (t2 - t1 * t1 * (1.0f / NUM_GRAPHS)) * (1.0f / (NUM_GRAPHS - 1));
        V[t] = var;
    }
    __syncthreads();

    if (t == 0) {
        float tot = 0.f;
        #pragma unroll
        for (int k = 0; k < NUM_ATOMS; k++) tot += V[k];
        out[0] = -0.01f * (tot * (1.0f / NUM_ATOMS));
    }
}

extern "C" void kernel_launch(void* const* d_in, const int* in_sizes, int n_in,
                              void* d_out, int out_size, void* d_ws, size_t ws_size,
                              hipStream_t stream) {
    const float* codes = (const float*)d_in[0];
    const int*   batch = (const int*)d_in[1];
    int total_nodes = in_sizes[0] / NUM_ATOMS;

    float4* means = (float4*)d_ws;                       // 256 KB
    int*    offs  = (int*)((char*)d_ws + NUM_GRAPHS * 16 * sizeof(float4));  // 4.1 KB

    bounds_kernel<<<(NUM_GRAPHS + 1 + 255) / 256, 256, 0, stream>>>(batch, offs, total_nodes);

    graph_mean_kernel<<<NUM_GRAPHS, 512, 0, stream>>>(
        (const float4*)codes, offs, means, total_nodes);

    finalize_kernel<<<1, 1024, 0, stream>>>((const float*)means, (float*)d_out);
}

// Round 5
// 96.441 us; speedup vs baseline: 1.7488x; 1.2508x over previous
//
#include <hip/hip_runtime.h>
#include <hip/hip_bf16.h>

#define NUM_GRAPHS 1024
#define NUM_ATOMS  64

// Native clang vector type: __builtin_nontemporal_load requires it
// (HIP_vector_type float4 is a struct and is rejected).
typedef float f4 __attribute__((ext_vector_type(4)));

// Kernel 0: segment boundaries via parallel transition scan (no dependent
// binary-search chains). offs[g] = first node index of graph g; offs[1024]=N.
__global__ void __launch_bounds__(256)
bounds_scan_kernel(const int* __restrict__ batch, int* __restrict__ offs, int total_nodes) {
    int i = blockIdx.x * blockDim.x + threadIdx.x;
    if (i >= total_nodes) return;
    int b = batch[i];
    if (i == 0) {
        for (int g = 0; g <= b; ++g) offs[g] = 0;
    }
    if (i + 1 < total_nodes) {
        int nb = batch[i + 1];
        if (nb != b) {
            for (int g = b + 1; g <= nb; ++g) offs[g] = i + 1;
        }
    } else {
        for (int g = b + 1; g <= NUM_GRAPHS; ++g) offs[g] = total_nodes;
    }
}

// Kernel 1: one block per graph. Stream-reduce codes[s0:s1, :], write the mean.
// Block = 512 threads: t = 16*q + r, q in [0,32) node sub-index, r in [0,16)
// float4 column group. 4x unrolled, non-temporal (stream-once) loads.
__global__ void __launch_bounds__(512)
graph_mean_kernel(const f4* __restrict__ codes4,     // [nodes][16] f4
                  const int* __restrict__ offs,      // [NUM_GRAPHS+1]
                  f4* __restrict__ means,            // [NUM_GRAPHS][16] f4
                  int total_nodes) {
    int g = blockIdx.x;
    int s0 = offs[g];
    int s1 = offs[g + 1];

    int t = threadIdx.x;
    int r = t & 15;
    int q = t >> 4;

    const f4* p = codes4 + (long long)(s0 + q) * 16 + r;
    int n = s0 + q;

    f4 a0 = (f4)(0.f), a1 = (f4)(0.f), a2 = (f4)(0.f), a3 = (f4)(0.f);

    // Bulk: 4 nodes per thread per iteration (block covers 128 nodes/step).
    while (n + 96 < s1) {
        f4 v0 = __builtin_nontemporal_load(p);
        f4 v1 = __builtin_nontemporal_load(p + 512);
        f4 v2 = __builtin_nontemporal_load(p + 1024);
        f4 v3 = __builtin_nontemporal_load(p + 1536);
        a0 += v0; a1 += v1; a2 += v2; a3 += v3;
        n += 128; p += 2048;
    }
    // Tail
    while (n < s1) {
        f4 v = __builtin_nontemporal_load(p);
        a0 += v;
        n += 32; p += 512;
    }

    f4 acc = (a0 + a1) + (a2 + a3);

    // Reduce 32 node-subgroups per column. Row padded to 17 f4.
    __shared__ f4 red[32][17];
    red[q][r] = acc;
    __syncthreads();

    if (t < 16) {
        f4 tot = (f4)(0.f);
        #pragma unroll
        for (int k = 0; k < 32; k++) tot += red[k][t];
        float inv = 1.0f / (float)(s1 - s0);
        means[g * 16 + t] = tot * inv;
    }
}

// Kernel 2: per-atom unbiased variance over 1024 graph means, mean over atoms,
// * -0.01. One block, 1024 threads, f4-vectorized (16 iters/thread).
__global__ void __launch_bounds__(1024)
finalize_kernel(const f4* __restrict__ means4,  // [NUM_GRAPHS][16] f4
                float* __restrict__ out) {
    __shared__ f4 S1[64][17];
    __shared__ f4 S2[64][17];
    __shared__ f4 V4[16];

    int t = threadIdx.x;
    int a4  = t & 15;   // f4 column (atoms 4*a4 .. 4*a4+3)
    int grp = t >> 4;   // graph group, [0,64)

    f4 s1 = (f4)(0.f);
    f4 s2 = (f4)(0.f);
    for (int g = grp; g < NUM_GRAPHS; g += 64) {
        f4 v = means4[g * 16 + a4];
        s1 += v;
        s2 += v * v;
    }
    S1[grp][a4] = s1;
    S2[grp][a4] = s2;
    __syncthreads();

    if (t < 16) {
        f4 t1 = (f4)(0.f);
        f4 t2 = (f4)(0.f);
        #pragma unroll
        for (int k = 0; k < 64; k++) { t1 += S1[k][t]; t2 += S2[k][t]; }
        const float invN  = 1.0f / NUM_GRAPHS;
        const float invN1 = 1.0f / (NUM_GRAPHS - 1);
        V4[t] = (t2 - t1 * t1 * invN) * invN1;
    }
    __syncthreads();

    if (t == 0) {
        float tot = 0.f;
        #pragma unroll
        for (int k = 0; k < 16; k++) {
            f4 v = V4[k];
            tot += (v.x + v.y) + (v.z + v.w);
        }
        out[0] = -0.01f * (tot * (1.0f / NUM_ATOMS));
    }
}

extern "C" void kernel_launch(void* const* d_in, const int* in_sizes, int n_in,
                              void* d_out, int out_size, void* d_ws, size_t ws_size,
                              hipStream_t stream) {
    const float* codes = (const float*)d_in[0];
    const int*   batch = (const int*)d_in[1];
    int total_nodes = in_sizes[0] / NUM_ATOMS;

    f4*  means = (f4*)d_ws;                                             // 256 KB
    int* offs  = (int*)((char*)d_ws + NUM_GRAPHS * 16 * sizeof(f4));    // 4.1 KB

    bounds_scan_kernel<<<(total_nodes + 255) / 256, 256, 0, stream>>>(batch, offs, total_nodes);

    graph_mean_kernel<<<NUM_GRAPHS, 512, 0, stream>>>(
        (const f4*)codes, offs, means, total_nodes);

    finalize_kernel<<<1, 1024, 0, stream>>>((const f4*)means, (float*)d_out);
}